// Round 6
// baseline (81.829 us; speedup 1.0000x reference)
//
#include <hip/hip_runtime.h>

// Depth-4 path signature, B=128, L=128, C=12, fp32.
// Round 6: R5's SGPR w-broadcast (s_load_dwordx16, scalar K$) kept — it
// freed the LDS pipe — but the occupancy bug is fixed: grid was 256 blocks
// = 1 block/CU = 1.75 waves/SIMD, fully latency-exposed. Now split each
// batch across 4 i-quarters -> 512 blocks, 448 threads (432 active =
// 3i x 12j x 12k, one k-chain and 12 level-4 accs per thread) -> 2
// blocks/CU, 3.5 waves/SIMD. Issue-bound ~8 us.
// No barriers in the 128-step main loop.

#define NC    12
#define NPTS  128
#define NSTEP 128            // 127 real increments + 1 zero pad (identity)
#define OUT_PER_B 22620      // 12 + 144 + 1728 + 20736
#define B1 384
#define B2 448               // 432 active = 3(i) * 12(j) * 12(k)
#define PADQ 33              // float4 row stride in LDS

typedef float vf16 __attribute__((ext_vector_type(16)));

// constant-foldable element access into the 3 SGPR vectors (e in [0,48))
#define WGET(e) ((e) < 16 ? w0[(e) & 15] : ((e) < 32 ? w1[(e) & 15] : w2[(e) & 15]))

__global__ __launch_bounds__(B1)
void prep_kernel(const float* __restrict__ path, float* __restrict__ Draw,
                 float* __restrict__ DTg) {
    const int b = blockIdx.x;
    const int t = threadIdx.x;        // < 384
    const int c  = t >> 5;            // 0..11
    const int sq = t & 31;            // 0..31
    const float* pb = path + (size_t)b * (NPTS * NC);
    float d[4];
    #pragma unroll
    for (int e = 0; e < 4; ++e) {
        int s = 4 * sq + e;
        d[e] = (s < NPTS - 1) ? (pb[(s + 1) * NC + c] - pb[s * NC + c]) : 0.f;
        Draw[(size_t)b * 1536 + s * NC + c] = d[e];
    }
    float4* dtg = (float4*)(DTg + (size_t)b * 1536 + c * NSTEP);
    dtg[sq] = make_float4(d[0], d[1], d[2], d[3]);
}

__global__ __launch_bounds__(B2, 4)
void sig_kernel(const float* __restrict__ Draw, const float* __restrict__ DTg,
                float* __restrict__ out) {
    const int bid = blockIdx.x;
    const int b  = bid >> 2;          // batch
    const int iq = bid & 3;           // i-quarter (3 i values)
    const int t  = threadIdx.x;

    __shared__ __align__(16) float4 DT4[NC * PADQ];   // 6336 B

    if (t < NC * 32) {
        int c = t >> 5, sq = t & 31;
        const float4* src = (const float4*)(DTg + (size_t)b * 1536 + c * NSTEP);
        DT4[c * PADQ + sq] = src[sq];
    }
    __syncthreads();

    // index map (pad threads duplicate work; stores guarded later)
    const int ta  = (t < 432) ? t : (t - 432);
    const int il  = ta / 144;          // 0..2
    const int rem = ta - il * 144;
    const int j   = rem / 12;          // 0..11
    const int k   = rem - j * 12;      // 0..11
    const int i   = iq * 3 + il;       // 0..11

    float acc[12];
    #pragma unroll
    for (int l = 0; l < 12; ++l) acc[l] = 0.f;
    float s3 = 0.f, s2 = 0.f, s1 = 0.f;

    // Uniformize the block's increment-table base address ONCE into an
    // SGPR pair; per-iteration offsets are immediates in the s_load.
    unsigned long long base_u;
    {
        unsigned long long a = (unsigned long long)(Draw + (size_t)b * 1536);
        unsigned int lo = __builtin_amdgcn_readfirstlane((unsigned int)a);
        unsigned int hi = __builtin_amdgcn_readfirstlane((unsigned int)(a >> 32));
        base_u = ((unsigned long long)hi << 32) | lo;
    }

    const float4* dti = &DT4[i * PADQ];
    const float4* dtj = &DT4[j * PADQ];
    const float4* dtk = &DT4[k * PADQ];

    for (int sq = 0; sq < NSTEP / 4; ++sq) {
        // block-uniform 48 increments for these 4 steps -> SGPRs via s_load.
        vf16 w0, w1, w2;
        {
            const float* wp = (const float*)(base_u + (unsigned long long)(sq * 192));
            asm volatile(
                "s_load_dwordx16 %0, %3, 0x0\n\t"
                "s_load_dwordx16 %1, %3, 0x40\n\t"
                "s_load_dwordx16 %2, %3, 0x80\n\t"
                "s_waitcnt lgkmcnt(0)"
                : "=&s"(w0), "=&s"(w1), "=&s"(w2)
                : "s"(wp));
        }

        // per-thread transposed reads (LDS, <=2-way conflict = free)
        float4 di4 = dti[sq];
        float4 dj4 = dtj[sq];
        float4 dk4 = dtk[sq];

        #pragma unroll
        for (int u = 0; u < 4; ++u) {
            const float di = (&di4.x)[u];
            const float dj = (&dj4.x)[u];
            const float dk = (&dk4.x)[u];

            // Horner-factored Chen step (identical arithmetic to R2/R3/R5)
            float A4 = (s1 + 0.25f * di) * (1.f / 3.f);
            float B4 = (s2 + dj * A4) * 0.5f;
            float C3 = s3 + dk * B4;

            #pragma unroll
            for (int l = 0; l < 12; ++l)
                acc[l] += C3 * WGET(12 * u + l);     // SGPR operand FMA

            float A3 = (s1 + di * (1.f / 3.f)) * 0.5f;
            float C2 = s2 + dj * A3;
            s3 += dk * C2;
            s2 += dj * (s1 + 0.5f * di);
            s1 += di;
        }
    }

    if (t < 432) {
        float* ob = out + (size_t)b * OUT_PER_B;
        if (j == 0 && k == 0) ob[i] = s1;                  // level 1
        if (k == 0) ob[12 + i * 12 + j] = s2;              // level 2
        const int ijk = (i * 12 + j) * 12 + k;
        ob[156 + ijk] = s3;                                // level 3
        float4* o4 = (float4*)(ob + 1884 + (size_t)ijk * 12);  // level 4, 48B
        o4[0] = make_float4(acc[0], acc[1], acc[2],  acc[3]);
        o4[1] = make_float4(acc[4], acc[5], acc[6],  acc[7]);
        o4[2] = make_float4(acc[8], acc[9], acc[10], acc[11]);
    }
}

extern "C" void kernel_launch(void* const* d_in, const int* in_sizes, int n_in,
                              void* d_out, int out_size, void* d_ws, size_t ws_size,
                              hipStream_t stream) {
    const float* path = (const float*)d_in[0];
    float* out = (float*)d_out;
    const int nbatch = in_sizes[0] / (NPTS * NC);   // = 128

    float* Draw = (float*)d_ws;                      // 128*1536 floats
    float* DTg  = Draw + (size_t)nbatch * 1536;      // 128*1536 floats

    prep_kernel<<<nbatch, B1, 0, stream>>>(path, Draw, DTg);
    sig_kernel<<<nbatch * 4, B2, 0, stream>>>(Draw, DTg, out);
}